// Round 2
// baseline (5292.272 us; speedup 1.0000x reference)
//
#include <hip/hip_runtime.h>
#include <hip/hip_bf16.h>
#include <cstdio>
#include <cstdint>

typedef __hip_bfloat16 bf16;

static __device__ __forceinline__ float b2f(bf16 v){ return __bfloat162float(v); }
static __device__ __forceinline__ bf16  f2b(float v){ return __float2bfloat16(v); }

static __device__ __forceinline__ float ldf(const float* p){ return *p; }
static __device__ __forceinline__ float ldf(const bf16* p){ return b2f(*p); }
static __device__ __forceinline__ void  stf(float* p, float v){ *p = v; }
static __device__ __forceinline__ void  stf(bf16*  p, float v){ *p = f2b(v); }

// ---------------- graph prep ----------------

__global__ void k_count(const int* __restrict__ dst, int* __restrict__ deg, int E){
  int e = blockIdx.x*256 + threadIdx.x;
  if(e<E) atomicAdd(&deg[dst[e]], 1);
}

__global__ void k_scan1(const int* __restrict__ deg, int* __restrict__ rp1, int* __restrict__ bsums, int N){
  __shared__ int s[256];
  int i = blockIdx.x*256 + threadIdx.x;
  int v = (i<N)? deg[i] : 0;
  s[threadIdx.x]=v; __syncthreads();
  for(int off=1; off<256; off<<=1){
    int t = (threadIdx.x>=off)? s[threadIdx.x-off] : 0;
    __syncthreads();
    s[threadIdx.x]+=t;
    __syncthreads();
  }
  if(i<N) rp1[i]=s[threadIdx.x];
  if(threadIdx.x==255) bsums[blockIdx.x]=s[255];
}

__global__ void k_scan2(const int* __restrict__ bsums, int* __restrict__ boffs, int NB){
  __shared__ int s[512];
  int x=threadIdx.x;
  int v = (x<NB)? bsums[x] : 0;
  s[x]=v; __syncthreads();
  for(int off=1; off<512; off<<=1){
    int t=(x>=off)? s[x-off]:0; __syncthreads();
    s[x]+=t; __syncthreads();
  }
  if(x<NB) boffs[x]=s[x]-v;  // exclusive prefix
}

__global__ void k_scan3(int* __restrict__ row_ptr, const int* __restrict__ boffs,
                        const int* __restrict__ deg, float* __restrict__ dis, int N){
  int i = blockIdx.x*256+threadIdx.x;
  if(i<N){
    row_ptr[i+1] += boffs[blockIdx.x];
    int d = deg[i];
    dis[i] = (d>0)? rsqrtf((float)d) : 0.f;
    if(i==0) row_ptr[0]=0;
  }
}

__global__ void k_fill(const int* __restrict__ src, const int* __restrict__ dst, const float* __restrict__ dis,
                       const int* __restrict__ row_ptr, int* __restrict__ cursor,
                       int* __restrict__ csr_src, float* __restrict__ csr_w, int E){
  int e = blockIdx.x*256+threadIdx.x;
  if(e<E){
    int d = dst[e], s = src[e];
    int pos = row_ptr[d] + atomicAdd(&cursor[d], 1);
    csr_src[pos]=s;
    csr_w[pos]=dis[s]*dis[d];
  }
}

// ---------------- dense GEMM: C[Mx64] = A[MxK] @ W[Kx64] ----------------
// f32 accumulate; A is f32 or bf16; W f32; out f32 or bf16.

template<int K, typename AT, bool BOUT>
__global__ __launch_bounds__(256,2) void k_gemm(const AT* __restrict__ A, const float* __restrict__ W,
                                                float* __restrict__ Cf, bf16* __restrict__ Cb, int M){
  __shared__ float sA[64][65];  // [row][k-within-chunk]
  __shared__ float sW[64][64];  // [k][col]
  const int t = threadIdx.x;
  const int m0 = blockIdx.x*64;
  const int tr = t>>4, tc = t&15;
  float acc[4][4] = {};
  for(int kc=0; kc<K/64; ++kc){
    #pragma unroll
    for(int it=0; it<16; ++it){
      int li = t + it*256;
      int r = li>>6, c = li&63;
      int m = m0 + r;
      float v = 0.f;
      if(m < M) v = ldf(&A[(size_t)m*K + kc*64 + c]);
      sA[r][c] = v;
    }
    #pragma unroll
    for(int it=0; it<16; ++it){
      int li = t + it*256;
      int r = li>>6, c = li&63;
      sW[r][c] = W[(size_t)(kc*64 + r)*64 + c];
    }
    __syncthreads();
    #pragma unroll 8
    for(int k=0;k<64;++k){
      float a0=sA[tr*4+0][k], a1=sA[tr*4+1][k], a2=sA[tr*4+2][k], a3=sA[tr*4+3][k];
      float w0=sW[k][tc*4+0], w1=sW[k][tc*4+1], w2=sW[k][tc*4+2], w3=sW[k][tc*4+3];
      acc[0][0]+=a0*w0; acc[0][1]+=a0*w1; acc[0][2]+=a0*w2; acc[0][3]+=a0*w3;
      acc[1][0]+=a1*w0; acc[1][1]+=a1*w1; acc[1][2]+=a1*w2; acc[1][3]+=a1*w3;
      acc[2][0]+=a2*w0; acc[2][1]+=a2*w1; acc[2][2]+=a2*w2; acc[2][3]+=a2*w3;
      acc[3][0]+=a3*w0; acc[3][1]+=a3*w1; acc[3][2]+=a3*w2; acc[3][3]+=a3*w3;
    }
    __syncthreads();
  }
  #pragma unroll
  for(int i=0;i<4;++i){
    int m = m0 + tr*4 + i;
    if(m<M){
      #pragma unroll
      for(int j=0;j<4;++j){
        int c = tc*4+j;
        if(BOUT) Cb[(size_t)m*64+c] = f2b(acc[i][j]);
        else     Cf[(size_t)m*64+c] = acc[i][j];
      }
    }
  }
}

// mix GEMM: A = [h(64, bf16) | x(128, f32)] (M x 192), W = [Wmix0 | Wmix1] (192 x (32+32))
// out: cols 0..31 -> Z0 (f32), cols 32..63 -> Z1 (bf16)
__global__ __launch_bounds__(256,2) void k_gemm_mix(const bf16* __restrict__ h, const float* __restrict__ x,
     const float* __restrict__ Wmix, float* __restrict__ Z0, bf16* __restrict__ Z1, int M){
  __shared__ float sA[64][65];
  __shared__ float sW[64][64];
  const int t=threadIdx.x, m0=blockIdx.x*64, tr=t>>4, tc=t&15;
  float acc[4][4]={};
  for(int kc=0;kc<3;++kc){
    #pragma unroll
    for(int it=0; it<16; ++it){
      int li=t+it*256; int r=li>>6, c=li&63;
      int m=m0+r; float v=0.f;
      if(m<M){
        int gk=kc*64+c;
        v = (gk<64)? b2f(h[(size_t)m*64+gk]) : x[(size_t)m*128 + (gk-64)];
      }
      sA[r][c]=v;
    }
    #pragma unroll
    for(int it=0; it<16; ++it){
      int li=t+it*256; int r=li>>6, c=li&63;
      int gk=kc*64+r;
      float v = (c<32)? Wmix[(size_t)gk*32 + c] : Wmix[6144 + (size_t)gk*32 + (c-32)];
      sW[r][c]=v;
    }
    __syncthreads();
    #pragma unroll 8
    for(int k=0;k<64;++k){
      float a0=sA[tr*4+0][k], a1=sA[tr*4+1][k], a2=sA[tr*4+2][k], a3=sA[tr*4+3][k];
      float w0=sW[k][tc*4+0], w1=sW[k][tc*4+1], w2=sW[k][tc*4+2], w3=sW[k][tc*4+3];
      acc[0][0]+=a0*w0; acc[0][1]+=a0*w1; acc[0][2]+=a0*w2; acc[0][3]+=a0*w3;
      acc[1][0]+=a1*w0; acc[1][1]+=a1*w1; acc[1][2]+=a1*w2; acc[1][3]+=a1*w3;
      acc[2][0]+=a2*w0; acc[2][1]+=a2*w1; acc[2][2]+=a2*w2; acc[2][3]+=a2*w3;
      acc[3][0]+=a3*w0; acc[3][1]+=a3*w1; acc[3][2]+=a3*w2; acc[3][3]+=a3*w3;
    }
    __syncthreads();
  }
  #pragma unroll
  for(int i=0;i<4;++i){
    int m=m0+tr*4+i;
    if(m<M){
      #pragma unroll
      for(int j=0;j<4;++j){
        int c=tc*4+j;
        if(c<32) Z0[(size_t)m*32+c]=acc[i][j];
        else     Z1[(size_t)m*32+(c-32)]=f2b(acc[i][j]);
      }
    }
  }
}

// ---------------- sparse prop + Clenshaw combine ----------------
// acc = sum_{in-edges e of v} w_e * Bin[src_e][f]   (L_hat t = -acc)
// MODE 0: out = Z - 2*acc
// MODE 1: out = Z - 2*acc - Bsub
// MODE 2: out = relu(Z - acc - Bsub + bias) + Zs + bias2
// MODE 3: out = Z - acc + bias
template<int F, int MODE, typename OT>
__global__ __launch_bounds__(256) void k_prop(const int* __restrict__ row_ptr, const int* __restrict__ csr_src,
    const float* __restrict__ csr_w, const bf16* __restrict__ Bin,
    const float* __restrict__ Z, const bf16* __restrict__ Bsub,
    const float* __restrict__ bias, const float* __restrict__ Zs, const float* __restrict__ bias2,
    OT* __restrict__ out, int N){
  constexpr int NPB = 256/F;
  int v = blockIdx.x*NPB + threadIdx.x/F;
  if(v>=N) return;
  int f = threadIdx.x % F;
  int e0=row_ptr[v], e1=row_ptr[v+1];
  float acc=0.f;
  for(int e=e0;e<e1;++e){
    acc += csr_w[e] * b2f(Bin[(size_t)csr_src[e]*F + f]);
  }
  size_t idx=(size_t)v*F+f;
  float r;
  if(MODE==0)      r = Z[idx] - 2.f*acc;
  else if(MODE==1) r = Z[idx] - 2.f*acc - b2f(Bsub[idx]);
  else if(MODE==2){ float tv = Z[idx] - acc - b2f(Bsub[idx]) + bias[f];
                    r = fmaxf(tv,0.f) + Zs[idx] + bias2[f]; }
  else             r = Z[idx] - acc + bias[f];
  stf(&out[idx], r);
}

// ---------------- host ----------------

template<typename AT>
static void launch_gemm(int K, bool bout, const AT* A, const float* W, float* Cf, bf16* Cb, int M, hipStream_t st){
  int grid=(M+63)/64;
  if(K==128){
    if(bout) k_gemm<128,AT,true ><<<grid,256,0,st>>>(A,W,Cf,Cb,M);
    else     k_gemm<128,AT,false><<<grid,256,0,st>>>(A,W,Cf,Cb,M);
  } else {
    if(bout) k_gemm<64,AT,true ><<<grid,256,0,st>>>(A,W,Cf,Cb,M);
    else     k_gemm<64,AT,false><<<grid,256,0,st>>>(A,W,Cf,Cb,M);
  }
}

extern "C" void kernel_launch(void* const* d_in, const int* in_sizes, int n_in,
                              void* d_out, int out_size, void* d_ws, size_t ws_size,
                              hipStream_t stream) {
  const int N = in_sizes[0]/128;     // 100000
  const int E = in_sizes[1]/2;       // 3200000

  const float* x    = (const float*)d_in[0];
  const int*   ei   = (const int*  )d_in[1];
  const float* W0   = (const float*)d_in[2];
  const float* b0   = (const float*)d_in[3];
  const float* Ws0  = (const float*)d_in[4];
  const float* bs0  = (const float*)d_in[5];
  const float* W1   = (const float*)d_in[6];
  const float* b1   = (const float*)d_in[7];
  const float* Ws1  = (const float*)d_in[8];
  const float* bs1  = (const float*)d_in[9];
  const float* W2   = (const float*)d_in[10];
  const float* b2   = (const float*)d_in[11];
  const float* Ws2  = (const float*)d_in[12];
  const float* bs2  = (const float*)d_in[13];
  const float* Wmix = (const float*)d_in[14];
  const float* bmix = (const float*)d_in[15];
  float* out = (float*)d_out;

  const int* src = ei;
  const int* dst = ei + E;

  // workspace carve (~142 MB; round-1 run proved ws_size covers this)
  size_t off=0;
  char* ws=(char*)d_ws;
  auto alloc=[&](size_t bytes)->void*{ void* p = ws+off; off=(off+bytes+255)&~(size_t)255; return p; };
  int*   csr_src = (int*)  alloc((size_t)E*4);
  float* csr_w   = (float*)alloc((size_t)E*4);
  int*   row_ptr = (int*)  alloc((size_t)(N+1)*4);
  int*   cursor  = (int*)  alloc((size_t)N*4);
  int*   deg     = (int*)  alloc((size_t)N*4);
  float* dis     = (float*)alloc((size_t)N*4);
  int*   bsums   = (int*)  alloc(2048);
  int*   boffs   = (int*)  alloc(2048);
  float* Zk      = (float*)alloc((size_t)N*64*4);
  float* Zs      = (float*)alloc((size_t)N*64*4);
  bf16*  Bb0     = (bf16*) alloc((size_t)N*64*2);
  bf16*  Bb1     = (bf16*) alloc((size_t)N*64*2);
  bf16*  Bb2     = (bf16*) alloc((size_t)N*64*2);
  bf16*  hA      = (bf16*) alloc((size_t)N*64*2);
  bf16*  hB      = (bf16*) alloc((size_t)N*64*2);
  if(off > ws_size){
    fprintf(stderr, "kernel_launch: workspace too small: need %zu, have %zu\n", off, ws_size);
    return;
  }

  const int NB   = (N+255)/256;   // 391
  const int gE   = (E+255)/256;
  const int gP64 = (N+3)/4;
  const int gP32 = (N+7)/8;

  // graph prep
  hipMemsetAsync(deg, 0, (size_t)N*4, stream);
  hipMemsetAsync(cursor, 0, (size_t)N*4, stream);
  k_count<<<gE,256,0,stream>>>(dst, deg, E);
  k_scan1<<<NB,256,0,stream>>>(deg, row_ptr+1, bsums, N);
  k_scan2<<<1,512,0,stream>>>(bsums, boffs, NB);
  k_scan3<<<NB,256,0,stream>>>(row_ptr, boffs, deg, dis, N);
  k_fill<<<gE,256,0,stream>>>(src, dst, dis, row_ptr, cursor, csr_src, csr_w, E);

  // one ChebConv layer via Clenshaw:
  // B5=Z5; B4=Z4-2a(B5); B3=Z3-2a(B4)-B5; B2=Z2-2a(B3)-B4; B1=Z1-2a(B2)-B3;
  // h' = relu(Z0 - a(B1) - B2 + b) + (h@Ws + bs)
  auto LAYER=[&](auto hin, int K, const float* W, const float* b, const float* Ws, const float* bs, bf16* hout){
    size_t WK=(size_t)K*64;
    launch_gemm(K,false,hin,Ws,    Zs,nullptr,N,stream);                    // skip branch
    launch_gemm(K,true ,hin,W+5*WK,nullptr,Bb0,N,stream);                   // B5
    launch_gemm(K,false,hin,W+4*WK,Zk,nullptr,N,stream);
    k_prop<64,0,bf16><<<gP64,256,0,stream>>>(row_ptr,csr_src,csr_w,Bb0,Zk,nullptr,nullptr,nullptr,nullptr,Bb1,N); // B4
    launch_gemm(K,false,hin,W+3*WK,Zk,nullptr,N,stream);
    k_prop<64,1,bf16><<<gP64,256,0,stream>>>(row_ptr,csr_src,csr_w,Bb1,Zk,Bb0,nullptr,nullptr,nullptr,Bb2,N);     // B3
    launch_gemm(K,false,hin,W+2*WK,Zk,nullptr,N,stream);
    k_prop<64,1,bf16><<<gP64,256,0,stream>>>(row_ptr,csr_src,csr_w,Bb2,Zk,Bb1,nullptr,nullptr,nullptr,Bb0,N);     // B2
    launch_gemm(K,false,hin,W+1*WK,Zk,nullptr,N,stream);
    k_prop<64,1,bf16><<<gP64,256,0,stream>>>(row_ptr,csr_src,csr_w,Bb0,Zk,Bb2,nullptr,nullptr,nullptr,Bb1,N);     // B1
    launch_gemm(K,false,hin,W+0*WK,Zk,nullptr,N,stream);
    k_prop<64,2,bf16><<<gP64,256,0,stream>>>(row_ptr,csr_src,csr_w,Bb1,Zk,Bb0,b,Zs,bs,hout,N);                    // h'
  };

  LAYER(x , 128, W0, b0, Ws0, bs0, hA);
  LAYER(hA,  64, W1, b1, Ws1, bs1, hB);
  LAYER(hB,  64, W2, b2, Ws2, bs2, hA);

  // mix head: out = Z0m + L_hat(Z1m) + bmix,  hcat = [hA | x]
  k_gemm_mix<<<(N+63)/64,256,0,stream>>>(hA, x, Wmix, Zk, Bb0, N);
  k_prop<32,3,float><<<gP32,256,0,stream>>>(row_ptr,csr_src,csr_w,Bb0,Zk,nullptr,bmix,nullptr,nullptr,out,N);
}

// Round 3
// 2595.058 us; speedup vs baseline: 2.0394x; 2.0394x over previous
//
#include <hip/hip_runtime.h>
#include <hip/hip_bf16.h>
#include <cstdio>
#include <cstdint>

typedef __hip_bfloat16 bf16;

static __device__ __forceinline__ float b2f(bf16 v){ return __bfloat162float(v); }
static __device__ __forceinline__ bf16  f2b(float v){ return __float2bfloat16(v); }

static __device__ __forceinline__ float ldf(const float* p){ return *p; }
static __device__ __forceinline__ float ldf(const bf16* p){ return b2f(*p); }
static __device__ __forceinline__ void  stf(float* p, float v){ *p = v; }
static __device__ __forceinline__ void  stf(bf16*  p, float v){ *p = f2b(v); }

// ---------------- graph prep ----------------

__global__ void k_count(const int* __restrict__ dst, int* __restrict__ deg, int E){
  int e = blockIdx.x*256 + threadIdx.x;
  if(e<E) atomicAdd(&deg[dst[e]], 1);
}

__global__ void k_scan1(const int* __restrict__ deg, int* __restrict__ rp1, int* __restrict__ bsums, int N){
  __shared__ int s[256];
  int i = blockIdx.x*256 + threadIdx.x;
  int v = (i<N)? deg[i] : 0;
  s[threadIdx.x]=v; __syncthreads();
  for(int off=1; off<256; off<<=1){
    int t = (threadIdx.x>=off)? s[threadIdx.x-off] : 0;
    __syncthreads();
    s[threadIdx.x]+=t;
    __syncthreads();
  }
  if(i<N) rp1[i]=s[threadIdx.x];
  if(threadIdx.x==255) bsums[blockIdx.x]=s[255];
}

__global__ void k_scan2(const int* __restrict__ bsums, int* __restrict__ boffs, int NB){
  __shared__ int s[512];
  int x=threadIdx.x;
  int v = (x<NB)? bsums[x] : 0;
  s[x]=v; __syncthreads();
  for(int off=1; off<512; off<<=1){
    int t=(x>=off)? s[x-off]:0; __syncthreads();
    s[x]+=t; __syncthreads();
  }
  if(x<NB) boffs[x]=s[x]-v;  // exclusive prefix
}

__global__ void k_scan3(int* __restrict__ row_ptr, const int* __restrict__ boffs,
                        const int* __restrict__ deg, float* __restrict__ dis, int N){
  int i = blockIdx.x*256+threadIdx.x;
  if(i<N){
    row_ptr[i+1] += boffs[blockIdx.x];
    int d = deg[i];
    dis[i] = (d>0)? rsqrtf((float)d) : 0.f;
    if(i==0) row_ptr[0]=0;
  }
}

__global__ void k_fill(const int* __restrict__ src, const int* __restrict__ dst, const float* __restrict__ dis,
                       const int* __restrict__ row_ptr, int* __restrict__ cursor,
                       int* __restrict__ csr_src, float* __restrict__ csr_w, int E){
  int e = blockIdx.x*256+threadIdx.x;
  if(e<E){
    int d = dst[e], s = src[e];
    int pos = row_ptr[d] + atomicAdd(&cursor[d], 1);
    csr_src[pos]=s;
    csr_w[pos]=dis[s]*dis[d];
  }
}

// ---------------- dense GEMM: C[Mx64] = A[MxK] @ W[Kx64] ----------------
// f32 accumulate; A is f32 or bf16; W f32; out f32 or bf16.
// sAT is transposed [k][row] so inner-loop reads are aligned ds_read_b128.

template<int K, typename AT, bool BOUT>
__global__ __launch_bounds__(256,2) void k_gemm(const AT* __restrict__ A, const float* __restrict__ W,
                                                float* __restrict__ Cf, bf16* __restrict__ Cb, int M){
  __shared__ float sAT[64][68]; // [k-within-chunk][row], pad 68 keeps float4 rows 16B-aligned
  __shared__ float sW[64][64];  // [k][col]
  const int t = threadIdx.x;
  const int m0 = blockIdx.x*64;
  const int tr = t>>4, tc = t&15;
  float acc[4][4] = {};
  for(int kc=0; kc<K/64; ++kc){
    #pragma unroll
    for(int it=0; it<16; ++it){
      int li = t + it*256;
      int r = li>>6, c = li&63;
      int m = m0 + r;
      float v = 0.f;
      if(m < M) v = ldf(&A[(size_t)m*K + kc*64 + c]);
      sAT[c][r] = v;
    }
    #pragma unroll
    for(int it=0; it<16; ++it){
      int li = t + it*256;
      int r = li>>6, c = li&63;
      sW[r][c] = W[(size_t)(kc*64 + r)*64 + c];
    }
    __syncthreads();
    #pragma unroll 8
    for(int k=0;k<64;++k){
      const float4 av = *reinterpret_cast<const float4*>(&sAT[k][tr*4]);
      const float4 wv = *reinterpret_cast<const float4*>(&sW[k][tc*4]);
      acc[0][0]+=av.x*wv.x; acc[0][1]+=av.x*wv.y; acc[0][2]+=av.x*wv.z; acc[0][3]+=av.x*wv.w;
      acc[1][0]+=av.y*wv.x; acc[1][1]+=av.y*wv.y; acc[1][2]+=av.y*wv.z; acc[1][3]+=av.y*wv.w;
      acc[2][0]+=av.z*wv.x; acc[2][1]+=av.z*wv.y; acc[2][2]+=av.z*wv.z; acc[2][3]+=av.z*wv.w;
      acc[3][0]+=av.w*wv.x; acc[3][1]+=av.w*wv.y; acc[3][2]+=av.w*wv.z; acc[3][3]+=av.w*wv.w;
    }
    __syncthreads();
  }
  #pragma unroll
  for(int i=0;i<4;++i){
    int m = m0 + tr*4 + i;
    if(m<M){
      #pragma unroll
      for(int j=0;j<4;++j){
        int c = tc*4+j;
        if(BOUT) Cb[(size_t)m*64+c] = f2b(acc[i][j]);
        else     Cf[(size_t)m*64+c] = acc[i][j];
      }
    }
  }
}

// mix GEMM: A = [h(64, bf16) | x(128, f32)] (M x 192), W = [Wmix0 | Wmix1] (192 x (32+32))
// out: cols 0..31 -> Z0 (f32), cols 32..63 -> Z1 (bf16)
__global__ __launch_bounds__(256,2) void k_gemm_mix(const bf16* __restrict__ h, const float* __restrict__ x,
     const float* __restrict__ Wmix, float* __restrict__ Z0, bf16* __restrict__ Z1, int M){
  __shared__ float sAT[64][68];
  __shared__ float sW[64][64];
  const int t=threadIdx.x, m0=blockIdx.x*64, tr=t>>4, tc=t&15;
  float acc[4][4]={};
  for(int kc=0;kc<3;++kc){
    #pragma unroll
    for(int it=0; it<16; ++it){
      int li=t+it*256; int r=li>>6, c=li&63;
      int m=m0+r; float v=0.f;
      if(m<M){
        int gk=kc*64+c;
        v = (gk<64)? b2f(h[(size_t)m*64+gk]) : x[(size_t)m*128 + (gk-64)];
      }
      sAT[c][r]=v;
    }
    #pragma unroll
    for(int it=0; it<16; ++it){
      int li=t+it*256; int r=li>>6, c=li&63;
      int gk=kc*64+r;
      float v = (c<32)? Wmix[(size_t)gk*32 + c] : Wmix[6144 + (size_t)gk*32 + (c-32)];
      sW[r][c]=v;
    }
    __syncthreads();
    #pragma unroll 8
    for(int k=0;k<64;++k){
      const float4 av = *reinterpret_cast<const float4*>(&sAT[k][tr*4]);
      const float4 wv = *reinterpret_cast<const float4*>(&sW[k][tc*4]);
      acc[0][0]+=av.x*wv.x; acc[0][1]+=av.x*wv.y; acc[0][2]+=av.x*wv.z; acc[0][3]+=av.x*wv.w;
      acc[1][0]+=av.y*wv.x; acc[1][1]+=av.y*wv.y; acc[1][2]+=av.y*wv.z; acc[1][3]+=av.y*wv.w;
      acc[2][0]+=av.z*wv.x; acc[2][1]+=av.z*wv.y; acc[2][2]+=av.z*wv.z; acc[2][3]+=av.z*wv.w;
      acc[3][0]+=av.w*wv.x; acc[3][1]+=av.w*wv.y; acc[3][2]+=av.w*wv.z; acc[3][3]+=av.w*wv.w;
    }
    __syncthreads();
  }
  #pragma unroll
  for(int i=0;i<4;++i){
    int m=m0+tr*4+i;
    if(m<M){
      #pragma unroll
      for(int j=0;j<4;++j){
        int c=tc*4+j;
        if(c<32) Z0[(size_t)m*32+c]=acc[i][j];
        else     Z1[(size_t)m*32+(c-32)]=f2b(acc[i][j]);
      }
    }
  }
}

// ---------------- sparse prop + Clenshaw combine ----------------
// acc = sum_{in-edges e of v} w_e * Bin[src_e][f]   (L_hat t = -acc)
// Edge loop unrolled x8: 8 independent row-gathers in flight per wave
// (round-2 counters: VALUBusy 19%, hbm 10% -> latency-bound at 1-deep MLP).
// MODE 0: out = Z - 2*acc
// MODE 1: out = Z - 2*acc - Bsub
// MODE 2: out = relu(Z - acc - Bsub + bias) + Zs + bias2
// MODE 3: out = Z - acc + bias
template<int F, int MODE, typename OT>
__global__ __launch_bounds__(256) void k_prop(const int* __restrict__ row_ptr, const int* __restrict__ csr_src,
    const float* __restrict__ csr_w, const bf16* __restrict__ Bin,
    const float* __restrict__ Z, const bf16* __restrict__ Bsub,
    const float* __restrict__ bias, const float* __restrict__ Zs, const float* __restrict__ bias2,
    OT* __restrict__ out, int N){
  constexpr int NPB = 256/F;
  int v = blockIdx.x*NPB + threadIdx.x/F;
  if(v>=N) return;
  int f = threadIdx.x % F;
  int e0=row_ptr[v], e1=row_ptr[v+1];
  float acc=0.f;
  int e=e0;
  for(; e+8<=e1; e+=8){
    float vv[8], ww[8];
    #pragma unroll
    for(int j=0;j<8;++j){
      int s = csr_src[e+j];
      ww[j] = csr_w[e+j];
      vv[j] = b2f(Bin[(size_t)s*F + f]);
    }
    #pragma unroll
    for(int j=0;j<8;++j) acc += ww[j]*vv[j];
  }
  for(; e<e1; ++e){
    acc += csr_w[e] * b2f(Bin[(size_t)csr_src[e]*F + f]);
  }
  size_t idx=(size_t)v*F+f;
  float r;
  if(MODE==0)      r = Z[idx] - 2.f*acc;
  else if(MODE==1) r = Z[idx] - 2.f*acc - b2f(Bsub[idx]);
  else if(MODE==2){ float tv = Z[idx] - acc - b2f(Bsub[idx]) + bias[f];
                    r = fmaxf(tv,0.f) + Zs[idx] + bias2[f]; }
  else             r = Z[idx] - acc + bias[f];
  stf(&out[idx], r);
}

// ---------------- host ----------------

template<typename AT>
static void launch_gemm(int K, bool bout, const AT* A, const float* W, float* Cf, bf16* Cb, int M, hipStream_t st){
  int grid=(M+63)/64;
  if(K==128){
    if(bout) k_gemm<128,AT,true ><<<grid,256,0,st>>>(A,W,Cf,Cb,M);
    else     k_gemm<128,AT,false><<<grid,256,0,st>>>(A,W,Cf,Cb,M);
  } else {
    if(bout) k_gemm<64,AT,true ><<<grid,256,0,st>>>(A,W,Cf,Cb,M);
    else     k_gemm<64,AT,false><<<grid,256,0,st>>>(A,W,Cf,Cb,M);
  }
}

extern "C" void kernel_launch(void* const* d_in, const int* in_sizes, int n_in,
                              void* d_out, int out_size, void* d_ws, size_t ws_size,
                              hipStream_t stream) {
  const int N = in_sizes[0]/128;     // 100000
  const int E = in_sizes[1]/2;       // 3200000

  const float* x    = (const float*)d_in[0];
  const int*   ei   = (const int*  )d_in[1];
  const float* W0   = (const float*)d_in[2];
  const float* b0   = (const float*)d_in[3];
  const float* Ws0  = (const float*)d_in[4];
  const float* bs0  = (const float*)d_in[5];
  const float* W1   = (const float*)d_in[6];
  const float* b1   = (const float*)d_in[7];
  const float* Ws1  = (const float*)d_in[8];
  const float* bs1  = (const float*)d_in[9];
  const float* W2   = (const float*)d_in[10];
  const float* b2   = (const float*)d_in[11];
  const float* Ws2  = (const float*)d_in[12];
  const float* bs2  = (const float*)d_in[13];
  const float* Wmix = (const float*)d_in[14];
  const float* bmix = (const float*)d_in[15];
  float* out = (float*)d_out;

  const int* src = ei;
  const int* dst = ei + E;

  // workspace carve (~142 MB)
  size_t off=0;
  char* ws=(char*)d_ws;
  auto alloc=[&](size_t bytes)->void*{ void* p = ws+off; off=(off+bytes+255)&~(size_t)255; return p; };
  int*   csr_src = (int*)  alloc((size_t)E*4);
  float* csr_w   = (float*)alloc((size_t)E*4);
  int*   row_ptr = (int*)  alloc((size_t)(N+1)*4);
  int*   cursor  = (int*)  alloc((size_t)N*4);
  int*   deg     = (int*)  alloc((size_t)N*4);
  float* dis     = (float*)alloc((size_t)N*4);
  int*   bsums   = (int*)  alloc(2048);
  int*   boffs   = (int*)  alloc(2048);
  float* Zk      = (float*)alloc((size_t)N*64*4);
  float* Zs      = (float*)alloc((size_t)N*64*4);
  bf16*  Bb0     = (bf16*) alloc((size_t)N*64*2);
  bf16*  Bb1     = (bf16*) alloc((size_t)N*64*2);
  bf16*  Bb2     = (bf16*) alloc((size_t)N*64*2);
  bf16*  hA      = (bf16*) alloc((size_t)N*64*2);
  bf16*  hB      = (bf16*) alloc((size_t)N*64*2);
  if(off > ws_size){
    fprintf(stderr, "kernel_launch: workspace too small: need %zu, have %zu\n", off, ws_size);
    return;
  }

  const int NB   = (N+255)/256;   // 391
  const int gE   = (E+255)/256;
  const int gP64 = (N+3)/4;
  const int gP32 = (N+7)/8;

  // graph prep
  hipMemsetAsync(deg, 0, (size_t)N*4, stream);
  hipMemsetAsync(cursor, 0, (size_t)N*4, stream);
  k_count<<<gE,256,0,stream>>>(dst, deg, E);
  k_scan1<<<NB,256,0,stream>>>(deg, row_ptr+1, bsums, N);
  k_scan2<<<1,512,0,stream>>>(bsums, boffs, NB);
  k_scan3<<<NB,256,0,stream>>>(row_ptr, boffs, deg, dis, N);
  k_fill<<<gE,256,0,stream>>>(src, dst, dis, row_ptr, cursor, csr_src, csr_w, E);

  // one ChebConv layer via Clenshaw:
  // B5=Z5; B4=Z4-2a(B5); B3=Z3-2a(B4)-B5; B2=Z2-2a(B3)-B4; B1=Z1-2a(B2)-B3;
  // h' = relu(Z0 - a(B1) - B2 + b) + (h@Ws + bs)
  auto LAYER=[&](auto hin, int K, const float* W, const float* b, const float* Ws, const float* bs, bf16* hout){
    size_t WK=(size_t)K*64;
    launch_gemm(K,false,hin,Ws,    Zs,nullptr,N,stream);                    // skip branch
    launch_gemm(K,true ,hin,W+5*WK,nullptr,Bb0,N,stream);                   // B5
    launch_gemm(K,false,hin,W+4*WK,Zk,nullptr,N,stream);
    k_prop<64,0,bf16><<<gP64,256,0,stream>>>(row_ptr,csr_src,csr_w,Bb0,Zk,nullptr,nullptr,nullptr,nullptr,Bb1,N); // B4
    launch_gemm(K,false,hin,W+3*WK,Zk,nullptr,N,stream);
    k_prop<64,1,bf16><<<gP64,256,0,stream>>>(row_ptr,csr_src,csr_w,Bb1,Zk,Bb0,nullptr,nullptr,nullptr,Bb2,N);     // B3
    launch_gemm(K,false,hin,W+2*WK,Zk,nullptr,N,stream);
    k_prop<64,1,bf16><<<gP64,256,0,stream>>>(row_ptr,csr_src,csr_w,Bb2,Zk,Bb1,nullptr,nullptr,nullptr,Bb0,N);     // B2
    launch_gemm(K,false,hin,W+1*WK,Zk,nullptr,N,stream);
    k_prop<64,1,bf16><<<gP64,256,0,stream>>>(row_ptr,csr_src,csr_w,Bb0,Zk,Bb2,nullptr,nullptr,nullptr,Bb1,N);     // B1
    launch_gemm(K,false,hin,W+0*WK,Zk,nullptr,N,stream);
    k_prop<64,2,bf16><<<gP64,256,0,stream>>>(row_ptr,csr_src,csr_w,Bb1,Zk,Bb0,b,Zs,bs,hout,N);                    // h'
  };

  LAYER(x , 128, W0, b0, Ws0, bs0, hA);
  LAYER(hA,  64, W1, b1, Ws1, bs1, hB);
  LAYER(hB,  64, W2, b2, Ws2, bs2, hA);

  // mix head: out = Z0m + L_hat(Z1m) + bmix,  hcat = [hA | x]
  k_gemm_mix<<<(N+63)/64,256,0,stream>>>(hA, x, Wmix, Zk, Bb0, N);
  k_prop<32,3,float><<<gP32,256,0,stream>>>(row_ptr,csr_src,csr_w,Bb0,Zk,nullptr,bmix,nullptr,nullptr,out,N);
}